// Round 3
// baseline (45.581 us; speedup 1.0000x reference)
//
#include <hip/hip_runtime.h>

// CenterlineLoss — symmetric masked chamfer distance, dot-product form.
// d^2(q,k) = |q|^2 + (|k|^2 - 2 q.k). Two launches total:
//   K1: fused key-transform + pairwise partial-min (both directions)
//   K2: combine + last-block-done final reduction

constexpr int NP = 16384;          // proj points
constexpr int NR = 8192;           // ref points
constexpr int CH = 256;            // key-chunk length
constexpr int S1 = NR / CH;        // 32 ref chunks   (dir1)
constexpr int S2 = NP / CH;        // 64 proj chunks  (dir2)
constexpr int BLK1 = NP / 1024;    // 16 query-blocks dir1
constexpr int BLK2 = NR / 1024;    // 8  query-blocks dir2
constexpr int G1 = BLK1 * S1;      // 512
constexpr int G2 = BLK2 * S2;      // 512
constexpr float FMAX = 3.4e38f;

// ---- K1: fused transform + pairwise partial-min ----
__global__ __launch_bounds__(256) void k_pair(const float* __restrict__ proj,
                                              const float* __restrict__ ref,
                                              float* __restrict__ part1,
                                              float* __restrict__ part2,
                                              unsigned* __restrict__ counter) {
    __shared__ float4 sh[CH];
    int tid = threadIdx.x;
    int bx = blockIdx.x;
    if (bx == 0 && tid == 0) *counter = 0u;   // reset for K2 (stream-ordered)

    bool d1 = bx < G1;
    int cb = d1 ? bx : bx - G1;
    int pb = cb & ((d1 ? BLK1 : BLK2) - 1);   // query-block index
    int ck = cb >> (d1 ? 4 : 3);              // key-chunk index

    // stage keys with on-the-fly transform
    int kidx = ck * CH + tid;
    if (d1) {
        float2 r = ((const float2*)ref)[kidx];
        // swapped ref (r.y, r.x) pairs with raw proj (p0, p1)
        sh[tid] = make_float4(-2.f * r.y, -2.f * r.x, fmaf(r.x, r.x, r.y * r.y), 0.f);
    } else {
        float2 p = ((const float2*)proj)[kidx];
        bool valid = (p.x >= 0.f) && (p.x <= 640.f) && (p.y >= 0.f) && (p.y <= 480.f);
        sh[tid] = valid ? make_float4(-2.f * p.x, -2.f * p.y, fmaf(p.x, p.x, p.y * p.y), 0.f)
                        : make_float4(0.f, 0.f, 1e30f, 0.f);
    }
    __syncthreads();

    int base = pb * 1024 + tid;
    const float2* qsrc = (const float2*)(d1 ? proj : ref);
    float2 q0 = qsrc[base];
    float2 q1 = qsrc[base + 256];
    float2 q2 = qsrc[base + 512];
    float2 q3 = qsrc[base + 768];
    if (!d1) {  // ref columns swapped
        float t;
        t = q0.x; q0.x = q0.y; q0.y = t;
        t = q1.x; q1.x = q1.y; q1.y = t;
        t = q2.x; q2.x = q2.y; q2.y = t;
        t = q3.x; q3.x = q3.y; q3.y = t;
    }

    float ma0 = FMAX, mb0 = FMAX, ma1 = FMAX, mb1 = FMAX;
    float ma2 = FMAX, mb2 = FMAX, ma3 = FMAX, mb3 = FMAX;
#pragma unroll 4
    for (int j = 0; j < CH; j += 4) {
        float4 k0 = sh[j], k1 = sh[j + 1], k2 = sh[j + 2], k3 = sh[j + 3];
        float t00 = fmaf(k0.y, q0.y, fmaf(k0.x, q0.x, k0.z));
        float t01 = fmaf(k1.y, q0.y, fmaf(k1.x, q0.x, k1.z));
        float t02 = fmaf(k2.y, q0.y, fmaf(k2.x, q0.x, k2.z));
        float t03 = fmaf(k3.y, q0.y, fmaf(k3.x, q0.x, k3.z));
        ma0 = fminf(fminf(ma0, t00), t01);
        mb0 = fminf(fminf(mb0, t02), t03);
        float t10 = fmaf(k0.y, q1.y, fmaf(k0.x, q1.x, k0.z));
        float t11 = fmaf(k1.y, q1.y, fmaf(k1.x, q1.x, k1.z));
        float t12 = fmaf(k2.y, q1.y, fmaf(k2.x, q1.x, k2.z));
        float t13 = fmaf(k3.y, q1.y, fmaf(k3.x, q1.x, k3.z));
        ma1 = fminf(fminf(ma1, t10), t11);
        mb1 = fminf(fminf(mb1, t12), t13);
        float t20 = fmaf(k0.y, q2.y, fmaf(k0.x, q2.x, k0.z));
        float t21 = fmaf(k1.y, q2.y, fmaf(k1.x, q2.x, k1.z));
        float t22 = fmaf(k2.y, q2.y, fmaf(k2.x, q2.x, k2.z));
        float t23 = fmaf(k3.y, q2.y, fmaf(k3.x, q2.x, k3.z));
        ma2 = fminf(fminf(ma2, t20), t21);
        mb2 = fminf(fminf(mb2, t22), t23);
        float t30 = fmaf(k0.y, q3.y, fmaf(k0.x, q3.x, k0.z));
        float t31 = fmaf(k1.y, q3.y, fmaf(k1.x, q3.x, k1.z));
        float t32 = fmaf(k2.y, q3.y, fmaf(k2.x, q3.x, k2.z));
        float t33 = fmaf(k3.y, q3.y, fmaf(k3.x, q3.x, k3.z));
        ma3 = fminf(fminf(ma3, t30), t31);
        mb3 = fminf(fminf(mb3, t32), t33);
    }

    float* part = d1 ? part1 : part2;
    int n = d1 ? NP : NR;
    part[ck * n + base]       = fminf(ma0, mb0);
    part[ck * n + base + 256] = fminf(ma1, mb1);
    part[ck * n + base + 512] = fminf(ma2, mb2);
    part[ck * n + base + 768] = fminf(ma3, mb3);
}

// ---- K2: combine + last-block final ----
// blocks 0..63  : proj side -> bsum1[b], bcnt1[b]
// blocks 64..95 : ref side  -> bsum2[b-64]
// last block to finish re-reads partial sums and writes the scalar.
__global__ __launch_bounds__(256) void k_combine(const float* __restrict__ proj,
                                                 const float* __restrict__ ref,
                                                 const float* __restrict__ part1,
                                                 const float* __restrict__ part2,
                                                 float* __restrict__ bsum1,
                                                 float* __restrict__ bcnt1,
                                                 float* __restrict__ bsum2,
                                                 unsigned* __restrict__ counter,
                                                 float* __restrict__ out) {
    __shared__ float red[256];
    __shared__ float redc[256];
    __shared__ bool amLast;
    int tid = threadIdx.x;
    int b = blockIdx.x;
    if (b < 64) {
        int i = b * 256 + tid;
        float m = FMAX;
        for (int c = 0; c < S1; ++c) m = fminf(m, part1[c * NP + i]);
        float2 p = ((const float2*)proj)[i];
        bool valid = (p.x >= 0.f) && (p.x <= 640.f) && (p.y >= 0.f) && (p.y <= 480.f);
        float d = sqrtf(fmaxf(m + fmaf(p.x, p.x, p.y * p.y), 0.f));
        red[tid]  = valid ? d : 0.f;
        redc[tid] = valid ? 1.f : 0.f;
        __syncthreads();
        for (int w = 128; w > 0; w >>= 1) {
            if (tid < w) { red[tid] += red[tid + w]; redc[tid] += redc[tid + w]; }
            __syncthreads();
        }
        if (tid == 0) { bsum1[b] = red[0]; bcnt1[b] = redc[0]; }
    } else {
        int j = (b - 64) * 256 + tid;
        float m = FMAX;
        for (int c = 0; c < S2; ++c) m = fminf(m, part2[c * NR + j]);
        float2 r = ((const float2*)ref)[j];
        red[tid] = sqrtf(fmaxf(m + fmaf(r.x, r.x, r.y * r.y), 0.f));
        __syncthreads();
        for (int w = 128; w > 0; w >>= 1) {
            if (tid < w) red[tid] += red[tid + w];
            __syncthreads();
        }
        if (tid == 0) bsum2[b - 64] = red[0];
    }

    // last-block-done final reduction (deterministic: fixed-topology sums)
    __threadfence();
    if (tid == 0) {
        unsigned old = atomicAdd(counter, 1u);
        amLast = (old == 95u);
    }
    __syncthreads();
    if (amLast) {
        __threadfence();
        float v1 = (tid < 64) ? bsum1[tid] : 0.f;
        float vc = (tid < 64) ? bcnt1[tid] : 0.f;
        float v2 = (tid < 32) ? bsum2[tid] : 0.f;
        red[tid] = v1;
        redc[tid] = vc;
        __syncthreads();
        for (int w = 128; w > 0; w >>= 1) {
            if (tid < w) { red[tid] += red[tid + w]; redc[tid] += redc[tid + w]; }
            __syncthreads();
        }
        float s1 = red[0], c1 = redc[0];
        __syncthreads();
        red[tid] = v2;
        __syncthreads();
        for (int w = 128; w > 0; w >>= 1) {
            if (tid < w) red[tid] += red[tid + w];
            __syncthreads();
        }
        if (tid == 0) out[0] = 0.5f * (s1 / c1 + red[0] / (float)NR);
    }
}

extern "C" void kernel_launch(void* const* d_in, const int* in_sizes, int n_in,
                              void* d_out, int out_size, void* d_ws, size_t ws_size,
                              hipStream_t stream) {
    const float* proj = (const float*)d_in[0];   // 16384 x 2
    const float* ref  = (const float*)d_in[1];   // 8192 x 2
    float* out = (float*)d_out;

    float* ws = (float*)d_ws;
    float*    part1   = ws;                        // S1*NP = 524288
    float*    part2   = part1 + S1 * NP;           // S2*NR = 524288
    float*    bsum1   = part2 + S2 * NR;           // 64
    float*    bcnt1   = bsum1 + 64;                // 64
    float*    bsum2   = bcnt1 + 64;                // 32
    unsigned* counter = (unsigned*)(bsum2 + 32);   // 1

    k_pair<<<G1 + G2, 256, 0, stream>>>(proj, ref, part1, part2, counter);
    k_combine<<<96, 256, 0, stream>>>(proj, ref, part1, part2,
                                      bsum1, bcnt1, bsum2, counter, out);
}